// Round 3
// baseline (1038.322 us; speedup 1.0000x reference)
//
#include <hip/hip_runtime.h>
#include <hip/hip_bf16.h>
#include <stdint.h>

// Encoder_LSTM: 4 zero-state LSTM cells on gathered packed rows.
// gates = x @ W_ih^T + (b_ih + b_hh); f-gate unused -> compute only i,g,o panels.
// All GEMMs are [N x 512] @ [512 x 512]^T per gate, bf16 MFMA, fp32 epilogue.

#define HH 512
#define T_STEPS 512
#define NG 1536          // i,g,o rows of the reordered weight matrix
#define BM 128
#define BN 64
#define BK 64

typedef __attribute__((ext_vector_type(8))) short bf16x8s;   // 8 bf16 (4 VGPRs)
typedef __attribute__((ext_vector_type(8))) unsigned short ushort8;
typedef __attribute__((ext_vector_type(4))) float f32x4;
typedef unsigned short u16;

__device__ __forceinline__ u16 f2b(float f) {       // fp32 -> bf16, round-to-nearest-even
  union { float f; unsigned u; } v; v.f = f;
  unsigned u = v.u;
  unsigned r = u + 0x7fffu + ((u >> 16) & 1u);
  return (u16)(r >> 16);
}

__device__ __forceinline__ float sigm(float x) { return 1.f / (1.f + __expf(-x)); }
__device__ __forceinline__ float tanh_fast(float x) {
  float ax = fabsf(x);
  float e = __expf(-2.f * ax);            // in (0,1], no overflow possible
  float t = (1.f - e) / (1.f + e);
  return copysignf(t, x);
}

// ---- kernel 1: row map (reproduces idx = concat(i*bs[i] + arange(bs[i]))) ----
__global__ void k_rowmap(const int* __restrict__ bs, int* __restrict__ srcrow) {
  __shared__ int s_bs[T_STEPS];
  __shared__ int s_off[T_STEPS];
  int t = threadIdx.x;
  s_bs[t] = bs[t];
  __syncthreads();
  if (t == 0) {
    int acc = 0;
    for (int i = 0; i < T_STEPS; ++i) { s_off[i] = acc; acc += s_bs[i]; }
  }
  __syncthreads();
  int b = s_bs[t], off = s_off[t];
  for (int j = 0; j < b; ++j) srcrow[off + j] = t * b + j;
}

// ---- kernel 2: weight reorder (i,g,o panels) + convert to bf16; fused bias ----
__global__ void k_wconv(const float* __restrict__ W, const float* __restrict__ bih,
                        const float* __restrict__ bhh, u16* __restrict__ Wr,
                        float* __restrict__ bout) {
  int idx = blockIdx.x * blockDim.x + threadIdx.x;   // exactly NG*HH/4 threads
  int e = idx << 2;
  int rr = e >> 9;                // 0..1535 output row
  int c = e & (HH - 1);
  int src = rr + (rr >= 512 ? 512 : 0);  // i: 0..511 ; g: +512 -> 1024.. ; o: +512 -> 1536..
  float4 v = *(const float4*)(W + (size_t)src * HH + c);
  u16 o0 = f2b(v.x), o1 = f2b(v.y), o2 = f2b(v.z), o3 = f2b(v.w);
  ushort4 o = make_ushort4(o0, o1, o2, o3);
  *(ushort4*)(Wr + (size_t)rr * HH + c) = o;
  if (idx < NG) {
    int sb = idx + (idx >= 512 ? 512 : 0);
    bout[idx] = bih[sb] + bhh[sb];
  }
}

// ---- kernel 3: gather + fp32->bf16 of packed_x; zero-fill pad rows ----
__global__ void k_gather(const float* __restrict__ X, const int* __restrict__ srcrow,
                         u16* __restrict__ A0, int Ntot, int Mpad) {
  int idx = blockIdx.x * blockDim.x + threadIdx.x;   // Mpad*64 threads, 8 elems each
  int r = idx >> 6, c8 = (idx & 63) << 3;
  if (r >= Mpad) return;
  ushort8 o;
  if (r < Ntot) {
    const float* p = X + (size_t)srcrow[r] * HH + c8;
    float4 v0 = *(const float4*)p;
    float4 v1 = *(const float4*)(p + 4);
    o[0] = f2b(v0.x); o[1] = f2b(v0.y); o[2] = f2b(v0.z); o[3] = f2b(v0.w);
    o[4] = f2b(v1.x); o[5] = f2b(v1.y); o[6] = f2b(v1.z); o[7] = f2b(v1.w);
  } else {
#pragma unroll
    for (int j = 0; j < 8; ++j) o[j] = 0;   // keep pad rows finite through all layers
  }
  *(ushort8*)(A0 + (size_t)r * HH + c8) = o;
}

// ---- kernel 4: fused GEMM (3 gate panels) + LSTM activation epilogue ----
// Block: 128 rows x 64 h-cols; 4 waves (2x2), each wave 64x32 per gate panel.
__global__ __launch_bounds__(256, 2)
void k_lstm_gemm(const u16* __restrict__ A, const u16* __restrict__ Wr,
                 const float* __restrict__ bias,
                 float* __restrict__ h_out, float* __restrict__ c_out,
                 float* __restrict__ out0,
                 u16* __restrict__ h_next, int Ntot) {
  __shared__ __align__(16) u16 lA[BM * BK];        // [128][64] row-major, k contiguous
  __shared__ __align__(16) u16 lB[3 * BN * BK];    // [gate][64][64]

  const int tid = threadIdx.x;
  const int wid = tid >> 6, lane = tid & 63;
  const int wr = wid >> 1, wc = wid & 1;
  const int m0 = blockIdx.y * BM, n0 = blockIdx.x * BN;

  f32x4 acc[3][4][2];
#pragma unroll
  for (int g = 0; g < 3; ++g)
#pragma unroll
    for (int m = 0; m < 4; ++m)
#pragma unroll
      for (int n = 0; n < 2; ++n) acc[g][m][n] = (f32x4){0.f, 0.f, 0.f, 0.f};

  for (int kt = 0; kt < HH / BK; ++kt) {
    const int k0 = kt * BK;
    // ---- stage A(16KB) + B(24KB) via global_load_lds, 10 x 1KB chunks per wave ----
#pragma unroll
    for (int q = 0; q < 10; ++q) {
      int c = wid * 10 + q;                       // wave-uniform chunk id 0..39
      const u16* g;
      u16* l;
      if (c < 16) {                               // A chunk: 8 rows of 128B
        int row = (c << 3) + (lane >> 3);
        g = A + (size_t)(m0 + row) * HH + k0 + ((lane & 7) << 3);
        l = lA + (size_t)(c << 3) * BK;
      } else {
        int c2 = c - 16;
        int gs = c2 >> 3, cg = c2 & 7;
        int row = (cg << 3) + (lane >> 3);
        g = Wr + (size_t)((gs << 9) + n0 + row) * HH + k0 + ((lane & 7) << 3);
        l = lB + (size_t)((gs << 6) + (cg << 3)) * BK;
      }
      __builtin_amdgcn_global_load_lds(
          (const __attribute__((address_space(1))) unsigned int*)g,
          (__attribute__((address_space(3))) unsigned int*)l, 16, 0, 0);
    }
    __syncthreads();   // compiler drains vmcnt before s_barrier

    // ---- compute: 2 k-steps of 32, 24 MFMA each ----
#pragma unroll
    for (int kk = 0; kk < BK; kk += 32) {
      const int ko = kk + ((lane >> 4) << 3);
      bf16x8s af[4], bfr[3][2];
#pragma unroll
      for (int m = 0; m < 4; ++m) {
        int row = wr * 64 + m * 16 + (lane & 15);
        af[m] = *(const bf16x8s*)(lA + row * BK + ko);
      }
#pragma unroll
      for (int g = 0; g < 3; ++g)
#pragma unroll
        for (int n = 0; n < 2; ++n) {
          int row = wc * 32 + n * 16 + (lane & 15);
          bfr[g][n] = *(const bf16x8s*)(lB + (g * BN + row) * BK + ko);
        }
#pragma unroll
      for (int g = 0; g < 3; ++g)
#pragma unroll
        for (int m = 0; m < 4; ++m)
#pragma unroll
          for (int n = 0; n < 2; ++n)
            acc[g][m][n] = __builtin_amdgcn_mfma_f32_16x16x32_bf16(
                af[m], bfr[g][n], acc[g][m][n], 0, 0, 0);
    }
    __syncthreads();
  }

  // ---- epilogue: c = sig(i)*tanh(g), h = sig(o)*tanh(c) ----
  // C/D layout: col = lane&15, row = (lane>>4)*4 + j  [m89-verified]
  const int colb = n0 + wc * 32 + (lane & 15);
  const int rb0 = m0 + wr * 64 + ((lane >> 4) << 2);
#pragma unroll
  for (int n = 0; n < 2; ++n) {
    int col = colb + n * 16;
    float bi = bias[col], bg = bias[512 + col], bo = bias[1024 + col];
#pragma unroll
    for (int m = 0; m < 4; ++m) {
      int rbase = rb0 + m * 16;
#pragma unroll
      for (int j = 0; j < 4; ++j) {
        int r = rbase + j;
        float gi = acc[0][m][n][j] + bi;
        float gg = acc[1][m][n][j] + bg;
        float go = acc[2][m][n][j] + bo;
        float cv = sigm(gi) * tanh_fast(gg);
        float hv = sigm(go) * tanh_fast(cv);
        h_next[(size_t)r * HH + col] = f2b(hv);   // pad rows stay finite
        if (r < Ntot) {
          size_t off = (size_t)r * HH + col;
          h_out[off] = hv;
          c_out[off] = cv;
          if (out0) out0[off] = hv;
        }
      }
    }
  }
}

extern "C" void kernel_launch(void* const* d_in, const int* in_sizes, int n_in,
                              void* d_out, int out_size, void* d_ws, size_t ws_size,
                              hipStream_t stream) {
  const float* packed_x = (const float*)d_in[0];
  const int* bs = (const int*)d_in[1];
  const float* W_ih[4] = {(const float*)d_in[2], (const float*)d_in[6],
                          (const float*)d_in[10], (const float*)d_in[14]};
  const float* b_ih[4] = {(const float*)d_in[4], (const float*)d_in[8],
                          (const float*)d_in[12], (const float*)d_in[16]};
  const float* b_hh[4] = {(const float*)d_in[5], (const float*)d_in[9],
                          (const float*)d_in[13], (const float*)d_in[17]};

  const int Ntot = in_sizes[0] / HH;                 // 32643 packed rows
  const int Mpad = (Ntot + BM - 1) / BM * BM;        // 32768
  const size_t MH = (size_t)Ntot * HH;

  char* ws = (char*)d_ws;
  int* srcrow = (int*)ws;                            // Mpad * 4 B (=128KB)
  u16* A0 = (u16*)(ws + (size_t)Mpad * 4);           // Mpad*512 bf16 = 32 MB
  u16* A1 = A0 + (size_t)Mpad * HH;                  // 32 MB
  u16* Wr = A1 + (size_t)Mpad * HH;                  // 4 * 1536*512 bf16 = 6 MB
  float* bout = (float*)(Wr + (size_t)4 * NG * HH);  // 4 * 1536 f32

  float* out = (float*)d_out;   // [h4, h1, c1, h2, c2, h3, c3, h4, c4], each Ntot*512 f32

  k_rowmap<<<dim3(1), dim3(T_STEPS), 0, stream>>>(bs, srcrow);
  for (int l = 0; l < 4; ++l)
    k_wconv<<<dim3(NG * HH / 4 / 256), dim3(256), 0, stream>>>(
        W_ih[l], b_ih[l], b_hh[l], Wr + (size_t)l * NG * HH, bout + (size_t)l * NG);
  k_gather<<<dim3(Mpad * 64 / 256), dim3(256), 0, stream>>>(packed_x, srcrow, A0, Ntot, Mpad);

  dim3 grid(HH / BN, Mpad / BM);   // (8, 256)
  u16* Ain[4] = {A0, A1, A0, A1};
  u16* Anx[4] = {A1, A0, A1, A0};
  for (int l = 0; l < 4; ++l) {
    float* h_o = out + (size_t)(1 + 2 * l) * MH;
    float* c_o = out + (size_t)(2 + 2 * l) * MH;
    float* o0 = (l == 3) ? out : nullptr;
    k_lstm_gemm<<<grid, dim3(256), 0, stream>>>(
        Ain[l], Wr + (size_t)l * NG * HH, bout + (size_t)l * NG,
        h_o, c_o, o0, Anx[l], Ntot);
  }
}